// Round 2
// baseline (111.568 us; speedup 1.0000x reference)
//
#include <hip/hip_runtime.h>

#define NRES 384
#define NLIG 128
#define MCOPY 4
#define INC 384
#define MIDC 32
#define OUTC 128
#define NTOT 512

// ws layout (float offsets)
#define WS_RI   0           // [384][32]
#define WS_RJ   12288       // [384][32]
#define WS_LI   24576       // [m*128+r][32]
#define WS_LJ   40960       // [m*128+r][32]
#define WS_ARR  57344       // [384][y*128+o]
#define WS_ARL  1630208
#define WS_ALR  3203072
#define WS_ALL  4775936     // [m*128+il][y*128+o]
#define WS_WT   6873088     // 4 tensors x [x][y*128+o] (rr,rl,lr,ll)

// --- kA: fused W-transpose (blocks 0..127) + 1D projections (blocks 128..1023)
__global__ __launch_bounds__(256) void kA_prep(
    const float* __restrict__ rec, const float* __restrict__ lig,
    const float* __restrict__ rl1w, const float* __restrict__ rl1b,
    const float* __restrict__ rl2w, const float* __restrict__ rl2b,
    const float* __restrict__ ll1w, const float* __restrict__ ll1b,
    const float* __restrict__ ll2w, const float* __restrict__ ll2b,
    const float* __restrict__ Wrr, const float* __restrict__ Wrl,
    const float* __restrict__ Wlr, const float* __restrict__ Wll,
    float* __restrict__ ws) {
  __shared__ float lds[128 * 33];
  int b = blockIdx.x, t = threadIdx.x;
  if (b < 128) {
    int tensor = b >> 5, x = b & 31;
    const float* W = tensor == 0 ? Wrr : tensor == 1 ? Wrl : tensor == 2 ? Wlr : Wll;
    float* Wt = ws + WS_WT + tensor * 131072;
    for (int k = 0; k < 16; ++k) {
      int idx = k * 256 + t;       // 0..4095
      int o = idx >> 5, y = idx & 31;
      lds[o * 33 + y] = W[o * 1024 + x * 32 + y];
    }
    __syncthreads();
    for (int k = 0; k < 16; ++k) {
      int idx = k * 256 + t;       // = y*128+o
      int y = idx >> 7, o = idx & 127;
      Wt[x * 4096 + idx] = lds[o * 33 + y];
    }
    return;
  }
  // projections: one row per block; wave w handles channels w*16..w*16+15
  int r = b - 128;                 // 0..895
  const float* in;
  const float *w1, *b1, *w2, *b2;
  float *out1, *out2;
  if (r < NRES) {
    in = rec + (size_t)r * INC;
    out1 = ws + WS_RI + r * 32; out2 = ws + WS_RJ + r * 32;
    w1 = rl1w; b1 = rl1b; w2 = rl2w; b2 = rl2b;
  } else {
    int rl = r - NRES;             // 0..511 = m*128+nl
    in = lig + (size_t)rl * INC;
    out1 = ws + WS_LI + rl * 32; out2 = ws + WS_LJ + rl * 32;
    w1 = ll1w; b1 = ll1b; w2 = ll2w; b2 = ll2b;
  }
  int lane = t & 63, wid = t >> 6;
  float rv[6];
#pragma unroll
  for (int i = 0; i < 6; ++i) rv[i] = in[i * 64 + lane];
  for (int ci = 0; ci < 16; ++ci) {
    int c = wid * 16 + ci;         // 0..63
    int cc = c & 31;
    const float* wp = (c < 32 ? w1 : w2) + (size_t)cc * INC;
    float acc = 0.f;
#pragma unroll
    for (int i = 0; i < 6; ++i) acc += rv[i] * wp[i * 64 + lane];
#pragma unroll
    for (int m = 1; m < 64; m <<= 1) acc += __shfl_xor(acc, m, 64);
    if (lane == 0) {
      float bias = (c < 32 ? b1 : b2)[cc];
      (c < 32 ? out1 : out2)[cc] = acc + bias;
    }
  }
}

// --- k2: A[rows][y*128+o] = f[rows][x] @ Wt[x][y*128+o] (no LDS) -----------
__global__ __launch_bounds__(256) void k2_makeA(float* __restrict__ ws) {
  int b = blockIdx.x, t = threadIdx.x;
  const float* fac;
  const float* Wt;
  float* A;
  int local;
  if (b < 192)      { local = b;       fac = ws + WS_RI; A = ws + WS_ARR; Wt = ws + WS_WT + 0 * 131072; }
  else if (b < 384) { local = b - 192; fac = ws + WS_RI; A = ws + WS_ARL; Wt = ws + WS_WT + 1 * 131072; }
  else if (b < 576) { local = b - 384; fac = ws + WS_RJ; A = ws + WS_ALR; Wt = ws + WS_WT + 2 * 131072; }
  else              { local = b - 576; fac = ws + WS_LI; A = ws + WS_ALL; Wt = ws + WS_WT + 3 * 131072; }
  int itile = local >> 4, ctile = local & 15;
  int i0 = itile * 32, cb = ctile * 256;
  float acc[32];
#pragma unroll
  for (int r = 0; r < 32; ++r) acc[r] = 0.f;
  const float* Wp = Wt + cb + t;
  for (int x = 0; x < 32; ++x) {
    float wv = Wp[(size_t)x * 4096];
#pragma unroll
    for (int r = 0; r < 32; ++r) acc[r] += fac[(i0 + r) * 32 + x] * wv;
  }
  for (int r = 0; r < 32; ++r) A[(size_t)(i0 + r) * 4096 + cb + t] = acc[r];
}

// --- k3: all four quadrants; A read from global (L1/L2), fac in LDS --------
__global__ __launch_bounds__(256, 3) void k3_outer(
    const float* __restrict__ ws, float* __restrict__ out,
    const float* __restrict__ rrb, const float* __restrict__ rlb,
    const float* __restrict__ lrb, const float* __restrict__ llb) {
  __shared__ float fac[4096];      // top: [j=128][y=32]; ll: [m=4][j=32][y=32]
  int b = blockIdx.x, t = threadIdx.x;
  int og = t & 15, jg = t >> 4;
  int o0 = og * 8;
  const float4* fac4 = (const float4*)fac;

  if (b < 1920) {                  // rr / rl / lr
    const float* Arow;
    const float* bias;
    float* outbase;
    size_t jstride;
    if (b < 1152) {                // rr: i in [0,384), 3 j-tiles of 128
      int i = b / 3, jt = b - 3 * i;
      int j0 = jt * 128;
      Arow = ws + WS_ARR + (size_t)i * 4096;
      const float* rj = ws + WS_RJ + j0 * 32;
      for (int k = 0; k < 16; ++k) { int idx = k * 256 + t; fac[idx] = rj[idx]; }
      bias = rrb; outbase = out + ((size_t)i * NTOT + j0) * OUTC; jstride = OUTC;
    } else if (b < 1536) {         // rl
      int i = b - 1152;
      Arow = ws + WS_ARL + (size_t)i * 4096;
      const float* lj = ws + WS_LJ;
      for (int k = 0; k < 16; ++k) {
        int idx = k * 256 + t;
        fac[idx] = 0.25f * (lj[idx] + lj[4096 + idx] + lj[8192 + idx] + lj[12288 + idx]);
      }
      bias = rlb; outbase = out + ((size_t)i * NTOT + NRES) * OUTC; jstride = OUTC;
    } else {                       // lr (transposed output)
      int i = b - 1536;
      Arow = ws + WS_ALR + (size_t)i * 4096;
      const float* li = ws + WS_LI;
      for (int k = 0; k < 16; ++k) {
        int idx = k * 256 + t;
        fac[idx] = 0.25f * (li[idx] + li[4096 + idx] + li[8192 + idx] + li[12288 + idx]);
      }
      bias = lrb; outbase = out + ((size_t)NRES * NTOT + i) * OUTC; jstride = (size_t)NTOT * OUTC;
    }
    __syncthreads();
    const float4* Ag = (const float4*)Arow;
    int j0g = jg * 8;
    float acc[8][8];
#pragma unroll
    for (int jj = 0; jj < 8; ++jj)
#pragma unroll
      for (int oo = 0; oo < 8; ++oo) acc[jj][oo] = 0.f;

    for (int yb = 0; yb < 8; ++yb) {
      float af[4][8];
#pragma unroll
      for (int dy = 0; dy < 4; ++dy) {
        int y = yb * 4 + dy;
        float4 u = Ag[y * 32 + og * 2];
        float4 v = Ag[y * 32 + og * 2 + 1];
        af[dy][0] = u.x; af[dy][1] = u.y; af[dy][2] = u.z; af[dy][3] = u.w;
        af[dy][4] = v.x; af[dy][5] = v.y; af[dy][6] = v.z; af[dy][7] = v.w;
      }
#pragma unroll
      for (int jj = 0; jj < 8; ++jj) {
        float4 fv = fac4[(j0g + jj) * 8 + yb];
        float fvf[4] = {fv.x, fv.y, fv.z, fv.w};
#pragma unroll
        for (int dy = 0; dy < 4; ++dy)
#pragma unroll
          for (int oo = 0; oo < 8; ++oo) acc[jj][oo] += fvf[dy] * af[dy][oo];
      }
    }
    float4 b0 = *(const float4*)&bias[o0];
    float4 b1 = *(const float4*)&bias[o0 + 4];
#pragma unroll
    for (int jj = 0; jj < 8; ++jj) {
      int j = j0g + jj;
      float* p = outbase + (size_t)j * jstride + o0;
      float4 v0, v1;
      v0.x = acc[jj][0] + b0.x; v0.y = acc[jj][1] + b0.y;
      v0.z = acc[jj][2] + b0.z; v0.w = acc[jj][3] + b0.w;
      v1.x = acc[jj][4] + b1.x; v1.y = acc[jj][5] + b1.y;
      v1.z = acc[jj][6] + b1.z; v1.w = acc[jj][7] + b1.w;
      *(float4*)p = v0;
      *(float4*)(p + 4) = v1;
    }
  } else {                         // ll: mean over m
    int bb = b - 1920;
    int il = bb >> 2, jt = bb & 3, j0 = jt * 32;
    const float* lj = ws + WS_LJ;
    for (int k = 0; k < 16; ++k) {
      int idx = k * 256 + t;       // m*1024 + (j*32+y)
      int m = idx >> 10, rem = idx & 1023;
      fac[idx] = lj[m * 4096 + j0 * 32 + rem];
    }
    __syncthreads();
    int j0g = jg * 2;
    float acc[2][8];
#pragma unroll
    for (int jj = 0; jj < 2; ++jj)
#pragma unroll
      for (int oo = 0; oo < 8; ++oo) acc[jj][oo] = 0.f;

    for (int m = 0; m < 4; ++m) {
      const float4* Ag = (const float4*)(ws + WS_ALL + (size_t)(m * 128 + il) * 4096);
      for (int yb = 0; yb < 8; ++yb) {
        float af[4][8];
#pragma unroll
        for (int dy = 0; dy < 4; ++dy) {
          int y = yb * 4 + dy;
          float4 u = Ag[y * 32 + og * 2];
          float4 v = Ag[y * 32 + og * 2 + 1];
          af[dy][0] = u.x; af[dy][1] = u.y; af[dy][2] = u.z; af[dy][3] = u.w;
          af[dy][4] = v.x; af[dy][5] = v.y; af[dy][6] = v.z; af[dy][7] = v.w;
        }
#pragma unroll
        for (int jj = 0; jj < 2; ++jj) {
          float4 fv = fac4[m * 256 + (j0g + jj) * 8 + yb];
          float fvf[4] = {fv.x, fv.y, fv.z, fv.w};
#pragma unroll
          for (int dy = 0; dy < 4; ++dy)
#pragma unroll
            for (int oo = 0; oo < 8; ++oo) acc[jj][oo] += fvf[dy] * af[dy][oo];
        }
      }
    }
    float4 b0 = *(const float4*)&llb[o0];
    float4 b1 = *(const float4*)&llb[o0 + 4];
#pragma unroll
    for (int jj = 0; jj < 2; ++jj) {
      int j = j0 + j0g + jj;
      float* p = out + ((size_t)(NRES + il) * NTOT + NRES + j) * OUTC + o0;
      float4 v0, v1;
      v0.x = 0.25f * acc[jj][0] + b0.x; v0.y = 0.25f * acc[jj][1] + b0.y;
      v0.z = 0.25f * acc[jj][2] + b0.z; v0.w = 0.25f * acc[jj][3] + b0.w;
      v1.x = 0.25f * acc[jj][4] + b1.x; v1.y = 0.25f * acc[jj][5] + b1.y;
      v1.z = 0.25f * acc[jj][6] + b1.z; v1.w = 0.25f * acc[jj][7] + b1.w;
      *(float4*)p = v0;
      *(float4*)(p + 4) = v1;
    }
  }
}

extern "C" void kernel_launch(void* const* d_in, const int* in_sizes, int n_in,
                              void* d_out, int out_size, void* d_ws, size_t ws_size,
                              hipStream_t stream) {
  const float* rec  = (const float*)d_in[0];
  const float* lig  = (const float*)d_in[1];
  const float* rl1w = (const float*)d_in[3];
  const float* rl1b = (const float*)d_in[4];
  const float* rl2w = (const float*)d_in[5];
  const float* rl2b = (const float*)d_in[6];
  const float* ll1w = (const float*)d_in[7];
  const float* ll1b = (const float*)d_in[8];
  const float* ll2w = (const float*)d_in[9];
  const float* ll2b = (const float*)d_in[10];
  const float* rrw  = (const float*)d_in[11];
  const float* rrb  = (const float*)d_in[12];
  const float* rlw  = (const float*)d_in[13];
  const float* rlb  = (const float*)d_in[14];
  const float* lrw  = (const float*)d_in[15];
  const float* lrb  = (const float*)d_in[16];
  const float* llw  = (const float*)d_in[17];
  const float* llb  = (const float*)d_in[18];
  float* out = (float*)d_out;
  float* ws  = (float*)d_ws;

  hipLaunchKernelGGL(kA_prep, dim3(1024), dim3(256), 0, stream,
                     rec, lig, rl1w, rl1b, rl2w, rl2b, ll1w, ll1b, ll2w, ll2b,
                     rrw, rlw, lrw, llw, ws);
  hipLaunchKernelGGL(k2_makeA, dim3(832), dim3(256), 0, stream, ws);
  hipLaunchKernelGGL(k3_outer, dim3(2432), dim3(256), 0, stream,
                     ws, out, rrb, rlb, lrb, llb);
}

// Round 3
// 92.219 us; speedup vs baseline: 1.2098x; 1.2098x over previous
//
#include <hip/hip_runtime.h>

#define NRES 384
#define NLIG 128
#define MCOPY 4
#define INC 384
#define MIDC 32
#define OUTC 128
#define NTOT 512

// ws layout (float offsets)
#define WS_RI   0           // [384][32]
#define WS_RJ   12288       // [384][32]
#define WS_LI   24576       // [m*128+r][32]
#define WS_LJ   40960       // [m*128+r][32]
#define WS_ARR  57344       // [384][y*128+o]
#define WS_ARL  1630208
#define WS_ALR  3203072
#define WS_ALL  4775936     // [m*128+il][y*128+o]
#define WS_WT   6873088     // 4 tensors x [x][y*128+o] (rr,rl,lr,ll)
#define WS_RJT  7397376     // [32][384]   rj transposed
#define WS_LJMT 7409664     // [32][128]   mean_m l_j, transposed
#define WS_LIMT 7413760     // [32][128]   mean_m l_i, transposed
#define WS_LJT  7417856     // [4][32][128] l_j transposed per m
// total = 7434240 floats = 29.74 MB

// --- kA: fused W-transpose (blocks 0..127) + 1D projections (128..1023) ----
__global__ __launch_bounds__(256) void kA_prep(
    const float* __restrict__ rec, const float* __restrict__ lig,
    const float* __restrict__ rl1w, const float* __restrict__ rl1b,
    const float* __restrict__ rl2w, const float* __restrict__ rl2b,
    const float* __restrict__ ll1w, const float* __restrict__ ll1b,
    const float* __restrict__ ll2w, const float* __restrict__ ll2b,
    const float* __restrict__ Wrr, const float* __restrict__ Wrl,
    const float* __restrict__ Wlr, const float* __restrict__ Wll,
    float* __restrict__ ws) {
  __shared__ float lds[128 * 33];
  int b = blockIdx.x, t = threadIdx.x;
  if (b < 128) {
    int tensor = b >> 5, x = b & 31;
    const float* W = tensor == 0 ? Wrr : tensor == 1 ? Wrl : tensor == 2 ? Wlr : Wll;
    float* Wt = ws + WS_WT + tensor * 131072;
    for (int k = 0; k < 16; ++k) {
      int idx = k * 256 + t;       // 0..4095
      int o = idx >> 5, y = idx & 31;
      lds[o * 33 + y] = W[o * 1024 + x * 32 + y];
    }
    __syncthreads();
    for (int k = 0; k < 16; ++k) {
      int idx = k * 256 + t;       // = y*128+o
      int y = idx >> 7, o = idx & 127;
      Wt[x * 4096 + idx] = lds[o * 33 + y];
    }
    return;
  }
  int r = b - 128;                 // 0..895
  const float* in;
  const float *w1, *b1, *w2, *b2;
  float *out1, *out2;
  if (r < NRES) {
    in = rec + (size_t)r * INC;
    out1 = ws + WS_RI + r * 32; out2 = ws + WS_RJ + r * 32;
    w1 = rl1w; b1 = rl1b; w2 = rl2w; b2 = rl2b;
  } else {
    int rl = r - NRES;
    in = lig + (size_t)rl * INC;
    out1 = ws + WS_LI + rl * 32; out2 = ws + WS_LJ + rl * 32;
    w1 = ll1w; b1 = ll1b; w2 = ll2w; b2 = ll2b;
  }
  int lane = t & 63, wid = t >> 6;
  float rv[6];
#pragma unroll
  for (int i = 0; i < 6; ++i) rv[i] = in[i * 64 + lane];
  for (int ci = 0; ci < 16; ++ci) {
    int c = wid * 16 + ci;
    int cc = c & 31;
    const float* wp = (c < 32 ? w1 : w2) + (size_t)cc * INC;
    float acc = 0.f;
#pragma unroll
    for (int i = 0; i < 6; ++i) acc += rv[i] * wp[i * 64 + lane];
#pragma unroll
    for (int m = 1; m < 64; m <<= 1) acc += __shfl_xor(acc, m, 64);
    if (lane == 0) {
      float bias = (c < 32 ? b1 : b2)[cc];
      (c < 32 ? out1 : out2)[cc] = acc + bias;
    }
  }
}

// --- k2: A = f @ Wt (blocks 0..831) + factor transposes (832..847) ---------
__global__ __launch_bounds__(256) void k2_makeA(float* __restrict__ ws) {
  int b = blockIdx.x, t = threadIdx.x;
  if (b >= 832) {
    if (b < 840) {                 // rjT[32][384]
      int y0 = (b - 832) * 4;
      const float* rj = ws + WS_RJ;
      float* dst = ws + WS_RJT + y0 * 384;
      for (int k = 0; k < 6; ++k) {
        int idx = k * 256 + t;     // 0..1535
        int y = y0 + idx / 384, j = idx % 384;
        dst[idx] = rj[j * 32 + y];
      }
    } else if (b < 842) {          // ljmT[32][128]
      const float* lj = ws + WS_LJ;
      for (int k = 0; k < 8; ++k) {
        int idx = (b - 840) * 2048 + k * 256 + t;
        int y = idx >> 7, j = idx & 127;
        int s = j * 32 + y;
        ws[WS_LJMT + idx] = 0.25f * (lj[s] + lj[4096 + s] + lj[8192 + s] + lj[12288 + s]);
      }
    } else if (b < 844) {          // limT[32][128]
      const float* li = ws + WS_LI;
      for (int k = 0; k < 8; ++k) {
        int idx = (b - 842) * 2048 + k * 256 + t;
        int y = idx >> 7, j = idx & 127;
        int s = j * 32 + y;
        ws[WS_LIMT + idx] = 0.25f * (li[s] + li[4096 + s] + li[8192 + s] + li[12288 + s]);
      }
    } else {                       // ljT[4][32][128]
      int m = b - 844;
      const float* lj = ws + WS_LJ + m * 4096;
      float* dst = ws + WS_LJT + m * 4096;
      for (int k = 0; k < 16; ++k) {
        int idx = k * 256 + t;
        int y = idx >> 7, j = idx & 127;
        dst[idx] = lj[j * 32 + y];
      }
    }
    return;
  }
  const float* fac;
  const float* Wt;
  float* A;
  int local;
  if (b < 192)      { local = b;       fac = ws + WS_RI; A = ws + WS_ARR; Wt = ws + WS_WT + 0 * 131072; }
  else if (b < 384) { local = b - 192; fac = ws + WS_RI; A = ws + WS_ARL; Wt = ws + WS_WT + 1 * 131072; }
  else if (b < 576) { local = b - 384; fac = ws + WS_RJ; A = ws + WS_ALR; Wt = ws + WS_WT + 2 * 131072; }
  else              { local = b - 576; fac = ws + WS_LI; A = ws + WS_ALL; Wt = ws + WS_WT + 3 * 131072; }
  int itile = local >> 4, ctile = local & 15;
  int i0 = itile * 32, cb = ctile * 256;
  float acc[32];
#pragma unroll
  for (int r = 0; r < 32; ++r) acc[r] = 0.f;
  const float* Wp = Wt + cb + t;
  for (int x = 0; x < 32; ++x) {
    float wv = Wp[(size_t)x * 4096];
#pragma unroll
    for (int r = 0; r < 32; ++r) acc[r] += fac[(i0 + r) * 32 + x] * wv;
  }
  for (int r = 0; r < 32; ++r) A[(size_t)(i0 + r) * 4096 + cb + t] = acc[r];
}

// --- k3_top: rr / rl / lr; A + facT both in LDS, conflict-free -------------
__global__ __launch_bounds__(256) void k3_top(
    const float* __restrict__ ws, float* __restrict__ out,
    const float* __restrict__ rrb, const float* __restrict__ rlb,
    const float* __restrict__ lrb) {
  __shared__ float A_lds[4096];    // [y=32][o=128]
  __shared__ float facT[4096];     // [y=32][j=128]
  int b = blockIdx.x, t = threadIdx.x;
  const float* Arow;
  const float* bias;
  float* outbase;
  size_t jstride;
  if (b < 1152) {                  // rr
    int i = b / 3, jt = b - 3 * i;
    int j0 = jt * 128;
    Arow = ws + WS_ARR + (size_t)i * 4096;
    const float* src = ws + WS_RJT;
    for (int k = 0; k < 16; ++k) {
      int idx = k * 256 + t;
      int y = idx >> 7, j = idx & 127;
      facT[idx] = src[y * 384 + j0 + j];
    }
    bias = rrb; outbase = out + ((size_t)i * NTOT + j0) * OUTC; jstride = OUTC;
  } else if (b < 1536) {           // rl
    int i = b - 1152;
    Arow = ws + WS_ARL + (size_t)i * 4096;
    const float* src = ws + WS_LJMT;
    for (int k = 0; k < 16; ++k) { int idx = k * 256 + t; facT[idx] = src[idx]; }
    bias = rlb; outbase = out + ((size_t)i * NTOT + NRES) * OUTC; jstride = OUTC;
  } else {                         // lr (transposed output)
    int i = b - 1536;
    Arow = ws + WS_ALR + (size_t)i * 4096;
    const float* src = ws + WS_LIMT;
    for (int k = 0; k < 16; ++k) { int idx = k * 256 + t; facT[idx] = src[idx]; }
    bias = lrb; outbase = out + ((size_t)NRES * NTOT + i) * OUTC; jstride = (size_t)NTOT * OUTC;
  }
  {
    float4* A4 = (float4*)A_lds;
    const float4* Ag = (const float4*)Arow;
#pragma unroll
    for (int k = 0; k < 4; ++k) A4[k * 256 + t] = Ag[k * 256 + t];
  }
  __syncthreads();

  int og = t & 15, jg = t >> 4;
  int o0 = og * 8, j0g = jg * 8;
  float acc[8][8];
#pragma unroll
  for (int jj = 0; jj < 8; ++jj)
#pragma unroll
    for (int oo = 0; oo < 8; ++oo) acc[jj][oo] = 0.f;

  for (int y = 0; y < 32; ++y) {
    float4 a0 = *(const float4*)&A_lds[y * 128 + o0];
    float4 a1 = *(const float4*)&A_lds[y * 128 + o0 + 4];
    float4 f0 = *(const float4*)&facT[y * 128 + j0g];
    float4 f1 = *(const float4*)&facT[y * 128 + j0g + 4];
    float av[8] = {a0.x, a0.y, a0.z, a0.w, a1.x, a1.y, a1.z, a1.w};
    float fv[8] = {f0.x, f0.y, f0.z, f0.w, f1.x, f1.y, f1.z, f1.w};
#pragma unroll
    for (int jj = 0; jj < 8; ++jj)
#pragma unroll
      for (int oo = 0; oo < 8; ++oo) acc[jj][oo] += fv[jj] * av[oo];
  }
  float4 b0 = *(const float4*)&bias[o0];
  float4 b1 = *(const float4*)&bias[o0 + 4];
#pragma unroll
  for (int jj = 0; jj < 8; ++jj) {
    int j = j0g + jj;
    float* p = outbase + (size_t)j * jstride + o0;
    float4 v0, v1;
    v0.x = acc[jj][0] + b0.x; v0.y = acc[jj][1] + b0.y;
    v0.z = acc[jj][2] + b0.z; v0.w = acc[jj][3] + b0.w;
    v1.x = acc[jj][4] + b1.x; v1.y = acc[jj][5] + b1.y;
    v1.z = acc[jj][6] + b1.z; v1.w = acc[jj][7] + b1.w;
    *(float4*)p = v0;
    *(float4*)(p + 4) = v1;
  }
}

// --- k3_ll: ll quadrant; blocks = (il, o-half, j-half) ---------------------
__global__ __launch_bounds__(256) void k3_ll(
    const float* __restrict__ ws, float* __restrict__ out,
    const float* __restrict__ llb) {
  __shared__ float A_lds[4 * 32 * 64];   // 32 KB [m][y][64 o]
  __shared__ float facT[4 * 32 * 64];    // 32 KB [m][y][64 j]
  int b = blockIdx.x, t = threadIdx.x;
  int il = b >> 2, oh = (b >> 1) & 1, jh = b & 1;
  {
    float4* A4 = (float4*)A_lds;
    float4* F4 = (float4*)facT;
#pragma unroll
    for (int k = 0; k < 8; ++k) {
      int idx4 = k * 256 + t;            // 0..2047
      int m = idx4 >> 9, rem = idx4 & 511, y = rem >> 4, c4 = rem & 15;
      const float4* As = (const float4*)(ws + WS_ALL + (size_t)(m * 128 + il) * 4096 + y * 128 + oh * 64);
      A4[idx4] = As[c4];
      const float4* Fs = (const float4*)(ws + WS_LJT + m * 4096 + y * 128 + jh * 64);
      F4[idx4] = Fs[c4];
    }
  }
  __syncthreads();
  int og = t & 7, jg = t >> 3;           // 8 o-groups x 32 j-groups
  int o0 = og * 8, j0 = jg * 2;
  float acc[2][8];
#pragma unroll
  for (int jj = 0; jj < 2; ++jj)
#pragma unroll
    for (int oo = 0; oo < 8; ++oo) acc[jj][oo] = 0.f;

  for (int my = 0; my < 128; ++my) {
    int base = my * 64;
    float4 a0 = *(const float4*)&A_lds[base + o0];
    float4 a1 = *(const float4*)&A_lds[base + o0 + 4];
    float f0 = facT[base + j0];
    float f1 = facT[base + j0 + 1];
    float av[8] = {a0.x, a0.y, a0.z, a0.w, a1.x, a1.y, a1.z, a1.w};
#pragma unroll
    for (int oo = 0; oo < 8; ++oo) acc[0][oo] += f0 * av[oo];
#pragma unroll
    for (int oo = 0; oo < 8; ++oo) acc[1][oo] += f1 * av[oo];
  }
  float4 b0 = *(const float4*)&llb[oh * 64 + o0];
  float4 b1 = *(const float4*)&llb[oh * 64 + o0 + 4];
#pragma unroll
  for (int jj = 0; jj < 2; ++jj) {
    int j = jh * 64 + j0 + jj;
    float* p = out + ((size_t)(NRES + il) * NTOT + NRES + j) * OUTC + oh * 64 + o0;
    float4 v0, v1;
    v0.x = 0.25f * acc[jj][0] + b0.x; v0.y = 0.25f * acc[jj][1] + b0.y;
    v0.z = 0.25f * acc[jj][2] + b0.z; v0.w = 0.25f * acc[jj][3] + b0.w;
    v1.x = 0.25f * acc[jj][4] + b1.x; v1.y = 0.25f * acc[jj][5] + b1.y;
    v1.z = 0.25f * acc[jj][6] + b1.z; v1.w = 0.25f * acc[jj][7] + b1.w;
    *(float4*)p = v0;
    *(float4*)(p + 4) = v1;
  }
}

extern "C" void kernel_launch(void* const* d_in, const int* in_sizes, int n_in,
                              void* d_out, int out_size, void* d_ws, size_t ws_size,
                              hipStream_t stream) {
  const float* rec  = (const float*)d_in[0];
  const float* lig  = (const float*)d_in[1];
  const float* rl1w = (const float*)d_in[3];
  const float* rl1b = (const float*)d_in[4];
  const float* rl2w = (const float*)d_in[5];
  const float* rl2b = (const float*)d_in[6];
  const float* ll1w = (const float*)d_in[7];
  const float* ll1b = (const float*)d_in[8];
  const float* ll2w = (const float*)d_in[9];
  const float* ll2b = (const float*)d_in[10];
  const float* rrw  = (const float*)d_in[11];
  const float* rrb  = (const float*)d_in[12];
  const float* rlw  = (const float*)d_in[13];
  const float* rlb  = (const float*)d_in[14];
  const float* lrw  = (const float*)d_in[15];
  const float* lrb  = (const float*)d_in[16];
  const float* llw  = (const float*)d_in[17];
  const float* llb  = (const float*)d_in[18];
  float* out = (float*)d_out;
  float* ws  = (float*)d_ws;

  hipLaunchKernelGGL(kA_prep, dim3(1024), dim3(256), 0, stream,
                     rec, lig, rl1w, rl1b, rl2w, rl2b, ll1w, ll1b, ll2w, ll2b,
                     rrw, rlw, lrw, llw, ws);
  hipLaunchKernelGGL(k2_makeA, dim3(848), dim3(256), 0, stream, ws);
  hipLaunchKernelGGL(k3_top, dim3(1920), dim3(256), 0, stream, ws, out, rrb, rlb, lrb);
  hipLaunchKernelGGL(k3_ll, dim3(512), dim3(256), 0, stream, ws, out, llb);
}

// Round 4
// 67.532 us; speedup vs baseline: 1.6521x; 1.3656x over previous
//
#include <hip/hip_runtime.h>

#define NRES 384
#define NLIG 128
#define INC 384
#define OUTC 128
#define NTOT 512

// ---- f32 ws regions (float offsets) ----
#define WS_RI   0           // [384][32]
#define WS_RJ   12288       // [384][32]
#define WS_LI   24576       // [m*128+r][32]
#define WS_LJ   40960       // [m*128+r][32]
#define WS_WT2  57344       // 4 tensors x [x][o*32+y]  (rr,rl,lr,ll)
#define WS_BF16 581632      // bf16 area starts here (float offset)

// ---- bf16 regions (bf16-element offsets from WS_BF16) ----
#define BT_RR   0            // [384][o*32+y]
#define BT_RL   1572864
#define BT_LR   3145728
#define BT_LL   4718592      // [m*128+il][o*32+y]
#define BF_RJ   6815744      // [384][32]
#define BF_LJM  6828032      // [128][32]  mean_m l_j
#define BF_LIM  6832128      // [128][32]  mean_m l_i
#define BF_LJ   6836224      // [4][128][32]
// end 6852608 elems -> total ws ~16.0 MB

typedef __bf16 bf16x8 __attribute__((ext_vector_type(8)));
typedef float  f32x4  __attribute__((ext_vector_type(4)));

// --- kA: Wt2 relayout (blocks 0..127) + 1D projections (128..1023) ---------
__global__ __launch_bounds__(256) void kA_prep(
    const float* __restrict__ rec, const float* __restrict__ lig,
    const float* __restrict__ rl1w, const float* __restrict__ rl1b,
    const float* __restrict__ rl2w, const float* __restrict__ rl2b,
    const float* __restrict__ ll1w, const float* __restrict__ ll1b,
    const float* __restrict__ ll2w, const float* __restrict__ ll2b,
    const float* __restrict__ Wrr, const float* __restrict__ Wrl,
    const float* __restrict__ Wlr, const float* __restrict__ Wll,
    float* __restrict__ ws) {
  int b = blockIdx.x, t = threadIdx.x;
  if (b < 128) {
    int tensor = b >> 5, x = b & 31;
    const float* W = tensor == 0 ? Wrr : tensor == 1 ? Wrl : tensor == 2 ? Wlr : Wll;
    float* Wt = ws + WS_WT2 + tensor * 131072 + x * 4096;
    for (int k = 0; k < 16; ++k) {
      int idx = k * 256 + t;       // = o*32+y
      int o = idx >> 5, y = idx & 31;
      Wt[idx] = W[o * 1024 + x * 32 + y];
    }
    return;
  }
  int r = b - 128;                 // 0..895
  const float* in;
  const float *w1, *b1, *w2, *b2;
  float *out1, *out2;
  if (r < NRES) {
    in = rec + (size_t)r * INC;
    out1 = ws + WS_RI + r * 32; out2 = ws + WS_RJ + r * 32;
    w1 = rl1w; b1 = rl1b; w2 = rl2w; b2 = rl2b;
  } else {
    int rl = r - NRES;
    in = lig + (size_t)rl * INC;
    out1 = ws + WS_LI + rl * 32; out2 = ws + WS_LJ + rl * 32;
    w1 = ll1w; b1 = ll1b; w2 = ll2w; b2 = ll2b;
  }
  int lane = t & 63, wid = t >> 6;
  float rv[6];
#pragma unroll
  for (int i = 0; i < 6; ++i) rv[i] = in[i * 64 + lane];
  for (int ci = 0; ci < 16; ++ci) {
    int c = wid * 16 + ci;
    int cc = c & 31;
    const float* wp = (c < 32 ? w1 : w2) + (size_t)cc * INC;
    float acc = 0.f;
#pragma unroll
    for (int i = 0; i < 6; ++i) acc += rv[i] * wp[i * 64 + lane];
#pragma unroll
    for (int m = 1; m < 64; m <<= 1) acc += __shfl_xor(acc, m, 64);
    if (lane == 0) {
      float bias = (c < 32 ? b1 : b2)[cc];
      (c < 32 ? out1 : out2)[cc] = acc + bias;
    }
  }
}

// --- k2: At_bf16 = f @ Wt2 (blocks 0..831) + bf16 factor tables (832..835) -
__global__ __launch_bounds__(256) void k2_makeA(float* __restrict__ ws) {
  int b = blockIdx.x, t = threadIdx.x;
  __bf16* B16 = (__bf16*)(ws + WS_BF16);
  if (b >= 832) {
    int tb = b - 832;
    if (tb == 0) {                 // rjB [384][32]
      const float* rj = ws + WS_RJ;
      __bf16* dst = B16 + BF_RJ;
      for (int k = 0; k < 48; ++k) { int idx = k * 256 + t; dst[idx] = (__bf16)rj[idx]; }
    } else if (tb == 1) {          // ljmB + limB [128][32]
      const float* lj = ws + WS_LJ;
      const float* li = ws + WS_LI;
      __bf16* dm = B16 + BF_LJM;
      __bf16* di = B16 + BF_LIM;
      for (int k = 0; k < 16; ++k) {
        int idx = k * 256 + t;
        dm[idx] = (__bf16)(0.25f * (lj[idx] + lj[4096 + idx] + lj[8192 + idx] + lj[12288 + idx]));
        di[idx] = (__bf16)(0.25f * (li[idx] + li[4096 + idx] + li[8192 + idx] + li[12288 + idx]));
      }
    } else {                       // ljB [4][128][32]
      const float* lj = ws + WS_LJ;
      __bf16* dst = B16 + BF_LJ;
      int base = (tb - 2) * 8192;
      for (int k = 0; k < 32; ++k) { int idx = base + k * 256 + t; dst[idx] = (__bf16)lj[idx]; }
    }
    return;
  }
  const float* fac;
  const float* Wt;
  __bf16* At;
  int local;
  if (b < 192)      { local = b;       fac = ws + WS_RI; At = B16 + BT_RR; Wt = ws + WS_WT2 + 0 * 131072; }
  else if (b < 384) { local = b - 192; fac = ws + WS_RI; At = B16 + BT_RL; Wt = ws + WS_WT2 + 1 * 131072; }
  else if (b < 576) { local = b - 384; fac = ws + WS_RJ; At = B16 + BT_LR; Wt = ws + WS_WT2 + 2 * 131072; }
  else              { local = b - 576; fac = ws + WS_LI; At = B16 + BT_LL; Wt = ws + WS_WT2 + 3 * 131072; }
  int itile = local >> 4, ctile = local & 15;
  int i0 = itile * 32, cb = ctile * 256;
  float acc[32];
#pragma unroll
  for (int r = 0; r < 32; ++r) acc[r] = 0.f;
  const float* Wp = Wt + cb + t;
  for (int x = 0; x < 32; ++x) {
    float wv = Wp[(size_t)x * 4096];
#pragma unroll
    for (int r = 0; r < 32; ++r) acc[r] += fac[(i0 + r) * 32 + x] * wv;
  }
  for (int r = 0; r < 32; ++r) At[(size_t)(i0 + r) * 4096 + cb + t] = (__bf16)acc[r];
}

// --- k3: all four quadrants via MFMA, fragments straight from global -------
__global__ __launch_bounds__(256) void k3_mfma(
    const float* __restrict__ ws, float* __restrict__ out,
    const float* __restrict__ rrb, const float* __restrict__ rlb,
    const float* __restrict__ lrb, const float* __restrict__ llb) {
  const __bf16* B16 = (const __bf16*)(ws + WS_BF16);
  int b = blockIdx.x, t = threadIdx.x;
  int l = t & 63, w = t >> 6;
  int lr16 = l & 15, lq = l >> 4;

  if (b < 1920) {                  // rr / rl / lr  (K = 32, one mfma per tile)
    const __bf16* At;
    const __bf16* fc;
    const float* bias;
    float* outp;
    size_t jstr;
    if (b < 1152) {                // rr: i in [0,384), 3 j-tiles of 128
      int i = b / 3, jt = b - 3 * i;
      At = B16 + BT_RR + (size_t)i * 4096;
      fc = B16 + BF_RJ + jt * 4096;
      bias = rrb; outp = out + ((size_t)i * NTOT + jt * 128) * OUTC; jstr = OUTC;
    } else if (b < 1536) {         // rl
      int i = b - 1152;
      At = B16 + BT_RL + (size_t)i * 4096;
      fc = B16 + BF_LJM;
      bias = rlb; outp = out + ((size_t)i * NTOT + NRES) * OUTC; jstr = OUTC;
    } else {                       // lr (transposed output)
      int i = b - 1536;
      At = B16 + BT_LR + (size_t)i * 4096;
      fc = B16 + BF_LIM;
      bias = lrb; outp = out + (size_t)NRES * NTOT * OUTC + (size_t)i * OUTC;
      jstr = (size_t)NTOT * OUTC;
    }
    bf16x8 af[2];
#pragma unroll
    for (int jj = 0; jj < 2; ++jj)
      af[jj] = *(const bf16x8*)(fc + (size_t)(w * 32 + jj * 16 + lr16) * 32 + lq * 8);
    f32x4 acc[2][8];
#pragma unroll
    for (int jj = 0; jj < 2; ++jj)
#pragma unroll
      for (int ot = 0; ot < 8; ++ot) acc[jj][ot] = (f32x4){0.f, 0.f, 0.f, 0.f};
#pragma unroll
    for (int oc = 0; oc < 2; ++oc) {
      bf16x8 bv[4];
#pragma unroll
      for (int o4 = 0; o4 < 4; ++o4)
        bv[o4] = *(const bf16x8*)(At + (size_t)((oc * 4 + o4) * 16 + lr16) * 32 + lq * 8);
#pragma unroll
      for (int jj = 0; jj < 2; ++jj)
#pragma unroll
        for (int o4 = 0; o4 < 4; ++o4)
          acc[jj][oc * 4 + o4] =
              __builtin_amdgcn_mfma_f32_16x16x32_bf16(af[jj], bv[o4], acc[jj][oc * 4 + o4], 0, 0, 0);
    }
#pragma unroll
    for (int jj = 0; jj < 2; ++jj)
#pragma unroll
      for (int ot = 0; ot < 8; ++ot) {
        int col = ot * 16 + lr16;
        float bb = bias[col];
#pragma unroll
        for (int e = 0; e < 4; ++e) {
          int row = w * 32 + jj * 16 + 4 * lq + e;
          outp[(size_t)row * jstr + col] = acc[jj][ot][e] + bb;
        }
      }
  } else {                         // ll: K = 128 (4 m-slices of 32)
    int il = b - 1920;
    f32x4 acc[2][8];
#pragma unroll
    for (int jj = 0; jj < 2; ++jj)
#pragma unroll
      for (int ot = 0; ot < 8; ++ot) acc[jj][ot] = (f32x4){0.f, 0.f, 0.f, 0.f};
    for (int m = 0; m < 4; ++m) {
      const __bf16* At = B16 + BT_LL + (size_t)(m * 128 + il) * 4096;
      const __bf16* fc = B16 + BF_LJ + m * 4096;
      bf16x8 af[2];
#pragma unroll
      for (int jj = 0; jj < 2; ++jj)
        af[jj] = *(const bf16x8*)(fc + (size_t)(w * 32 + jj * 16 + lr16) * 32 + lq * 8);
#pragma unroll
      for (int oc = 0; oc < 2; ++oc) {
        bf16x8 bv[4];
#pragma unroll
        for (int o4 = 0; o4 < 4; ++o4)
          bv[o4] = *(const bf16x8*)(At + (size_t)((oc * 4 + o4) * 16 + lr16) * 32 + lq * 8);
#pragma unroll
        for (int jj = 0; jj < 2; ++jj)
#pragma unroll
          for (int o4 = 0; o4 < 4; ++o4)
            acc[jj][oc * 4 + o4] =
                __builtin_amdgcn_mfma_f32_16x16x32_bf16(af[jj], bv[o4], acc[jj][oc * 4 + o4], 0, 0, 0);
      }
    }
    float* outp = out + ((size_t)(NRES + il) * NTOT + NRES) * OUTC;
#pragma unroll
    for (int jj = 0; jj < 2; ++jj)
#pragma unroll
      for (int ot = 0; ot < 8; ++ot) {
        int col = ot * 16 + lr16;
        float bb = llb[col];
#pragma unroll
        for (int e = 0; e < 4; ++e) {
          int row = w * 32 + jj * 16 + 4 * lq + e;
          outp[(size_t)row * OUTC + col] = 0.25f * acc[jj][ot][e] + bb;
        }
      }
  }
}

extern "C" void kernel_launch(void* const* d_in, const int* in_sizes, int n_in,
                              void* d_out, int out_size, void* d_ws, size_t ws_size,
                              hipStream_t stream) {
  const float* rec  = (const float*)d_in[0];
  const float* lig  = (const float*)d_in[1];
  const float* rl1w = (const float*)d_in[3];
  const float* rl1b = (const float*)d_in[4];
  const float* rl2w = (const float*)d_in[5];
  const float* rl2b = (const float*)d_in[6];
  const float* ll1w = (const float*)d_in[7];
  const float* ll1b = (const float*)d_in[8];
  const float* ll2w = (const float*)d_in[9];
  const float* ll2b = (const float*)d_in[10];
  const float* rrw  = (const float*)d_in[11];
  const float* rrb  = (const float*)d_in[12];
  const float* rlw  = (const float*)d_in[13];
  const float* rlb  = (const float*)d_in[14];
  const float* lrw  = (const float*)d_in[15];
  const float* lrb  = (const float*)d_in[16];
  const float* llw  = (const float*)d_in[17];
  const float* llb  = (const float*)d_in[18];
  float* out = (float*)d_out;
  float* ws  = (float*)d_ws;

  hipLaunchKernelGGL(kA_prep, dim3(1024), dim3(256), 0, stream,
                     rec, lig, rl1w, rl1b, rl2w, rl2b, ll1w, ll1b, ll2w, ll2b,
                     rrw, rlw, lrw, llw, ws);
  hipLaunchKernelGGL(k2_makeA, dim3(836), dim3(256), 0, stream, ws);
  hipLaunchKernelGGL(k3_mfma, dim3(2048), dim3(256), 0, stream,
                     ws, out, rrb, rlb, lrb, llb);
}